// Round 9
// baseline (220.947 us; speedup 1.0000x reference)
//
#include <hip/hip_runtime.h>
#include <hip/hip_cooperative_groups.h>

namespace cg = cooperative_groups;

typedef short  sv8 __attribute__((ext_vector_type(8)));   // 8 bf16 (4 VGPRs)
typedef float  fv16 __attribute__((ext_vector_type(16))); // MFMA C/D
typedef unsigned int uv4 __attribute__((ext_vector_type(4)));
typedef unsigned int uint32;
typedef unsigned short ushort16;

#define NF      10
#define CIN     64
#define NTOT    8192              // T*H*W
#define HW      1024
#define FPAD    16                // feature dim padded for MFMA K
#define MSPLIT  8                 // m-splits (phase B -> phase C reduce)
#define MCHUNK  (NTOT / MSPLIT)   // 1024 m per block
#define PSTRIDE 16                // f-stride of partial buffer

// Native gfx950 shape: v_mfma_f32_32x32x16_bf16.
//   C/D: col=lane&31, row=(reg&3)+8*(reg>>2)+4*(lane>>5)   [measured]
//   A:   i=lane&31,   k=8*(lane>>5)+j                      [validated R8]
//   B:   j=lane&31,   k=8*(lane>>5)+jj                     [validated R8]
#define MFMA32(a, b, c) __builtin_amdgcn_mfma_f32_32x32x16_bf16((a), (b), (c), 0, 0, 0)

static __device__ inline ushort16 f32_to_bf16_rne(float x) {
    uint32 u = __builtin_bit_cast(uint32, x);
    u = (u + 0x7fffu + ((u >> 16) & 1u)) >> 16;
    return (ushort16)u;
}

// ---------------------------------------------------------------------------
// Fused cooperative kernel: grid 512 x 256 (2 blocks/CU co-resident).
//   Phase A (blocks 0..63): qkv projections -> bf16 ws (wave-based port of R8)
//   Phase B (all 512): 32x32x16 MFMA attention -> pws partials (R8 structure)
//   Phase C (first 81920 threads): reduce partials -> out
// grid.sync() between phases (device-scope fence + barrier).
// ---------------------------------------------------------------------------
__global__ __launch_bounds__(256, 2) void fused_kernel(
    const float* __restrict__ in1, const float* __restrict__ in2,
    const float* __restrict__ w1, const float* __restrict__ b1,
    const float* __restrict__ w2, const float* __restrict__ b2,
    const float* __restrict__ w3, const float* __restrict__ b3,
    ushort16* __restrict__ qb, ushort16* __restrict__ kb,
    ushort16* __restrict__ vfrag, float* __restrict__ pws,
    float* __restrict__ out)
{
    cg::grid_group grid = cg::this_grid();

    const int wid  = threadIdx.x >> 6;
    const int lane = threadIdx.x & 63;

    __shared__ ushort16 lvs[4][64][FPAD];              // per-wave v staging, 8 KB

    // ======================= Phase A: projections ==========================
    if (blockIdx.x < 64) {
        const int wg   = blockIdx.x * 4 + wid;         // 0..255
        const int side = wg >> 7;                      // 0: q+v(in1), 1: k(in2)
        const int g64  = wg & 127;                     // 64-row group
        const int n    = g64 * 64 + lane;
        const int t    = n >> 10;
        const int hw   = n & 1023;

        if (side == 0) {
            const float* p = in1 + (size_t)t * (CIN * HW) + hw;
            float aq[NF], av[NF];
#pragma unroll
            for (int f = 0; f < NF; ++f) { aq[f] = b1[f]; av[f] = b3[f]; }
            for (int c0 = 0; c0 < CIN; c0 += 16) {
                float a[16];
#pragma unroll
                for (int j = 0; j < 16; ++j) a[j] = p[(c0 + j) * HW];
#pragma unroll
                for (int j = 0; j < 16; ++j) {
#pragma unroll
                    for (int f = 0; f < NF; ++f) {
                        aq[f] = fmaf(w1[f * CIN + c0 + j], a[j], aq[f]);
                        av[f] = fmaf(w3[f * CIN + c0 + j], a[j], av[f]);
                    }
                }
            }
            ushort16 row[FPAD];
#pragma unroll
            for (int f = 0; f < NF; ++f) row[f] = f32_to_bf16_rne(aq[f]);
#pragma unroll
            for (int f = NF; f < FPAD; ++f) row[f] = 0;   // K-pad MUST be zero
            ushort16* dq = qb + (size_t)n * FPAD;
            ((uint4*)dq)[0] = ((const uint4*)row)[0];
            ((uint4*)dq)[1] = ((const uint4*)row)[1];

            // v: wave-private LDS staging, then PV A-fragment emit
#pragma unroll
            for (int f = 0; f < NF; ++f) lvs[wid][lane][f] = f32_to_bf16_rne(av[f]);
            // within-wave LDS dep: compiler inserts lgkmcnt wait; no barrier
            const int l  = lane & 31;                     // f-slot
            const int tl = lane >> 5;                     // local 32-m tile
            char* base = (char*)vfrag + ((size_t)(g64 * 2 + tl)) * 2048;
#pragma unroll
            for (int fs = 0; fs < 2; ++fs) {
#pragma unroll
                for (int hh = 0; hh < 2; ++hh) {
                    ushort16 buf[8];
#pragma unroll
                    for (int j = 0; j < 8; ++j)
                        buf[j] = (l < NF) ? lvs[wid][32 * tl + fs * 16 + 8 * hh + j][l]
                                          : (ushort16)0;
                    *(uint4*)(base + fs * 1024 + (hh * 32 + l) * 16) =
                        *(const uint4*)buf;
                }
            }
        } else {
            const float* p = in2 + (size_t)t * (CIN * HW) + hw;
            float ak[NF];
#pragma unroll
            for (int f = 0; f < NF; ++f) ak[f] = b2[f];
            for (int c0 = 0; c0 < CIN; c0 += 16) {
                float a[16];
#pragma unroll
                for (int j = 0; j < 16; ++j) a[j] = p[(c0 + j) * HW];
#pragma unroll
                for (int j = 0; j < 16; ++j) {
#pragma unroll
                    for (int f = 0; f < NF; ++f)
                        ak[f] = fmaf(w2[f * CIN + c0 + j], a[j], ak[f]);
                }
            }
            ushort16 row[FPAD];
#pragma unroll
            for (int f = 0; f < NF; ++f) row[f] = f32_to_bf16_rne(ak[f]);
#pragma unroll
            for (int f = NF; f < FPAD; ++f) row[f] = 0;
            ushort16* dk = kb + (size_t)n * FPAD;
            ((uint4*)dk)[0] = ((const uint4*)row)[0];
            ((uint4*)dk)[1] = ((const uint4*)row)[1];
        }
    }

    grid.sync();

    // ======================= Phase B: MFMA attention =======================
    {
        const int bx  = blockIdx.x & 63;               // n-group
        const int by  = blockIdx.x >> 6;               // m-split (0..7)
        const int col = lane & 31;
        const int h   = lane >> 5;
        const int n0  = (bx * 4 + wid) * 32;
        const int m0  = by * MCHUNK;

        const uint4 qraw = *(const uint4*)((const char*)qb + (size_t)(n0 + col) * 32 + h * 16);
        const sv8 qf = __builtin_bit_cast(sv8, qraw);

        const char* kbase = (const char*)kb + (size_t)(m0 + col) * 32 + h * 16;
        const char* vbase = (const char*)vfrag + (size_t)(m0 >> 5) * 2048 + lane * 16;

        fv16 zerov, acc1, acc2;
#pragma unroll
        for (int i = 0; i < 16; ++i) { zerov[i] = 0.f; acc1[i] = 0.f; acc2[i] = 0.f; }

        uint4 kf = *(const uint4*)kbase;
        uint4 v1 = *(const uint4*)vbase;
        uint4 v2 = *(const uint4*)(vbase + 1024);

        for (int s = 0; s < MCHUNK / 32; ++s) {
            // unconditional prefetch (last-step over-read stays inside ws)
            uint4 kf_n = *(const uint4*)(kbase + (size_t)(s + 1) * 1024);
            uint4 v1_n = *(const uint4*)(vbase + (size_t)(s + 1) * 2048);
            uint4 v2_n = *(const uint4*)(vbase + (size_t)(s + 1) * 2048 + 1024);

            fv16 S = MFMA32(__builtin_bit_cast(sv8, kf), qf, zerov);

            uint32 p[8];
#pragma unroll
            for (int i = 0; i < 8; ++i) {
                float e0 = fmaxf(S[2 * i], 0.f);
                float e1 = fmaxf(S[2 * i + 1], 0.f);
                p[i] = __builtin_amdgcn_perm(__builtin_bit_cast(uint32, e1),
                                             __builtin_bit_cast(uint32, e0), 0x07060302u);
            }
            uint32 sw[8];
#pragma unroll
            for (int i = 0; i < 8; ++i)
                sw[i] = __shfl_xor((unsigned int)p[i], 32, 64);

            uv4 b1 = { h ? sw[2] : p[0], h ? sw[3] : p[1],
                       h ? p[2] : sw[0], h ? p[3] : sw[1] };
            uv4 b2 = { h ? sw[6] : p[4], h ? sw[7] : p[5],
                       h ? p[6] : sw[4], h ? p[7] : sw[5] };

            acc1 = MFMA32(__builtin_bit_cast(sv8, v1), __builtin_bit_cast(sv8, b1), acc1);
            acc2 = MFMA32(__builtin_bit_cast(sv8, v2), __builtin_bit_cast(sv8, b2), acc2);

            kf = kf_n; v1 = v1_n; v2 = v2_n;
        }

        const int n = n0 + col;
#pragma unroll
        for (int r = 0; r < 16; ++r) {
            int f = (r & 3) + 8 * (r >> 2) + 4 * h;
            if (f < NF)
                pws[((size_t)by * PSTRIDE + f) * NTOT + n] = acc1[r] + acc2[r];
        }
    }

    grid.sync();

    // ======================= Phase C: reduce ===============================
    {
        const int gid = blockIdx.x * 256 + threadIdx.x;    // < 131072
        if (gid < NF * NTOT) {
            const int f = gid >> 13;                       // / NTOT
            const int n = gid & (NTOT - 1);
            float s = 0.f;
#pragma unroll
            for (int y = 0; y < MSPLIT; ++y)
                s += pws[((size_t)y * PSTRIDE + f) * NTOT + n];
            const int t = n >> 10, hw = n & 1023;
            out[(size_t)t * (NF * HW) + f * HW + hw] = s;
        }
    }
}

extern "C" void kernel_launch(void* const* d_in, const int* in_sizes, int n_in,
                              void* d_out, int out_size, void* d_ws, size_t ws_size,
                              hipStream_t stream)
{
    const float* in1 = (const float*)d_in[0];
    const float* in2 = (const float*)d_in[1];
    const float* w1  = (const float*)d_in[2];
    const float* b1  = (const float*)d_in[3];
    const float* w2  = (const float*)d_in[4];
    const float* b2  = (const float*)d_in[5];
    const float* w3  = (const float*)d_in[6];
    const float* b3  = (const float*)d_in[7];

    // ws layout: qb (256K) | kb (256K) | vfrag (512K) | pws (4 MB fp32)
    ushort16* qb    = (ushort16*)d_ws;
    ushort16* kb    = qb + (size_t)NTOT * FPAD;
    ushort16* vfrag = kb + (size_t)NTOT * FPAD;
    float*    pws   = (float*)((char*)vfrag + 512 * 1024);
    float*    out   = (float*)d_out;

    void* args[] = {
        (void*)&in1, (void*)&in2,
        (void*)&w1, (void*)&b1, (void*)&w2, (void*)&b2, (void*)&w3, (void*)&b3,
        (void*)&qb, (void*)&kb, (void*)&vfrag, (void*)&pws, (void*)&out
    };
    hipLaunchCooperativeKernel((const void*)fused_kernel,
                               dim3(512), dim3(256), args, 0, stream);
}

// Round 10
// 105.673 us; speedup vs baseline: 2.0909x; 2.0909x over previous
//
#include <hip/hip_runtime.h>

typedef short  sv8 __attribute__((ext_vector_type(8)));   // 8 bf16 (4 VGPRs)
typedef float  fv16 __attribute__((ext_vector_type(16))); // MFMA C/D
typedef unsigned int uv4 __attribute__((ext_vector_type(4)));
typedef unsigned int uint32;
typedef unsigned short ushort16;

#define NF      10
#define CIN     64
#define NTOT    8192              // T*H*W
#define HW      1024
#define FPAD    16                // feature dim padded for MFMA K
#define MSPLIT  8                 // m-splits (partials via atomicAdd into out)
#define MCHUNK  (NTOT / MSPLIT)   // 1024 m per block

// Native gfx950 shape: v_mfma_f32_32x32x16_bf16 (validated end-to-end R8/R9).
//   C/D: col=lane&31, row=(reg&3)+8*(reg>>2)+4*(lane>>5)
//   A:   i=lane&31,   k=8*(lane>>5)+j
//   B:   j=lane&31,   k=8*(lane>>5)+jj
#define MFMA32(a, b, c) __builtin_amdgcn_mfma_f32_32x32x16_bf16((a), (b), (c), 0, 0, 0)

static __device__ inline ushort16 f32_to_bf16_rne(float x) {
    uint32 u = __builtin_bit_cast(uint32, x);
    u = (u + 0x7fffu + ((u >> 16) & 1u)) >> 16;
    return (ushort16)u;
}

// ---------------------------------------------------------------------------
// Stage 1: projections -> bf16 workspace  PLUS zero-init of out (atomic
// accumulation target; harness poisons it to 0xAA before every launch).
// Stream ordering of the two dispatches makes the zeroes visible to stage 2.
// grid (NTOT/64, 2), block 64. y=0: q+v from in1; y=1: k from in2.
// vfrag layout (validated R8): per 32-m tile tau, two 1KB A-frags (fs=0,1):
//   byte addr = tau*2048 + fs*1024 + (h*32+f)*16  holds 8 bf16 =
//   v[f][m = 32*tau + fs*16 + 8h + j], j=0..7; f>=10 slots zero.
// ---------------------------------------------------------------------------
__global__ __launch_bounds__(64) void qkv_kernel(
    const float* __restrict__ in1, const float* __restrict__ in2,
    const float* __restrict__ w1, const float* __restrict__ b1,
    const float* __restrict__ w2, const float* __restrict__ b2,
    const float* __restrict__ w3, const float* __restrict__ b3,
    ushort16* __restrict__ qb, ushort16* __restrict__ kb,
    ushort16* __restrict__ vfrag, float* __restrict__ out)
{
    __shared__ ushort16 lvs[64][FPAD];                 // v staging, 2 KB

    const int tid = threadIdx.x;

    // ---- zero the atomic target: 81920 floats / 16384 threads = 5 each
    {
        const int gid = (blockIdx.y * (NTOT / 64) + blockIdx.x) * 64 + tid;
#pragma unroll
        for (int i = 0; i < 5; ++i)
            out[(size_t)i * 16384 + gid] = 0.f;
    }

    const int n  = blockIdx.x * 64 + tid;
    const int t  = n >> 10;
    const int hw = n & 1023;

    if (blockIdx.y == 0) {
        const float* p = in1 + (size_t)t * (CIN * HW) + hw;
        float a[CIN];
#pragma unroll
        for (int c = 0; c < CIN; ++c) a[c] = p[c * HW];   // 64 loads in flight

        float aq[NF], av[NF];
#pragma unroll
        for (int f = 0; f < NF; ++f) { aq[f] = b1[f]; av[f] = b3[f]; }
#pragma unroll
        for (int c = 0; c < CIN; ++c) {
#pragma unroll
            for (int f = 0; f < NF; ++f) {
                aq[f] = fmaf(w1[f * CIN + c], a[c], aq[f]);
                av[f] = fmaf(w3[f * CIN + c], a[c], av[f]);
            }
        }
        ushort16 row[FPAD];
#pragma unroll
        for (int f = 0; f < NF; ++f) row[f] = f32_to_bf16_rne(aq[f]);
#pragma unroll
        for (int f = NF; f < FPAD; ++f) row[f] = 0;       // K-pad MUST be zero
        ushort16* dq = qb + (size_t)n * FPAD;
        ((uint4*)dq)[0] = ((const uint4*)row)[0];
        ((uint4*)dq)[1] = ((const uint4*)row)[1];

        // v: stage to LDS, then emit PV A-fragments
#pragma unroll
        for (int f = 0; f < NF; ++f) lvs[tid][f] = f32_to_bf16_rne(av[f]);
        __syncthreads();
        const int l  = tid & 31;                          // f-slot
        const int tl = tid >> 5;                          // local 32-m tile
        char* base = (char*)vfrag + ((size_t)(blockIdx.x * 2 + tl)) * 2048;
#pragma unroll
        for (int fs = 0; fs < 2; ++fs) {
#pragma unroll
            for (int hh = 0; hh < 2; ++hh) {
                ushort16 buf[8];
#pragma unroll
                for (int j = 0; j < 8; ++j)
                    buf[j] = (l < NF) ? lvs[32 * tl + fs * 16 + 8 * hh + j][l]
                                      : (ushort16)0;
                *(uint4*)(base + fs * 1024 + (hh * 32 + l) * 16) =
                    *(const uint4*)buf;
            }
        }
    } else {
        const float* p = in2 + (size_t)t * (CIN * HW) + hw;
        float a[CIN];
#pragma unroll
        for (int c = 0; c < CIN; ++c) a[c] = p[c * HW];

        float ak[NF];
#pragma unroll
        for (int f = 0; f < NF; ++f) ak[f] = b2[f];
#pragma unroll
        for (int c = 0; c < CIN; ++c) {
#pragma unroll
            for (int f = 0; f < NF; ++f) ak[f] = fmaf(w2[f * CIN + c], a[c], ak[f]);
        }
        ushort16 row[FPAD];
#pragma unroll
        for (int f = 0; f < NF; ++f) row[f] = f32_to_bf16_rne(ak[f]);
#pragma unroll
        for (int f = NF; f < FPAD; ++f) row[f] = 0;
        ushort16* dk = kb + (size_t)n * FPAD;
        ((uint4*)dk)[0] = ((const uint4*)row)[0];
        ((uint4*)dk)[1] = ((const uint4*)row)[1];
    }
}

// ---------------------------------------------------------------------------
// Stage 2: native 32x32x16 MFMA attention; epilogue atomicAdds fp32 partials
// straight into out (zeroed by stage 1) — no pws, no reduce kernel.
// grid (64, MSPLIT=8) = 512 blocks (2/CU), block 256 (4 waves, 32-n each).
// ---------------------------------------------------------------------------
__global__ __launch_bounds__(256) void attn_mfma_kernel(
    const ushort16* __restrict__ qb, const ushort16* __restrict__ kb,
    const ushort16* __restrict__ vfrag, float* __restrict__ out)
{
    const int lane = threadIdx.x & 63;
    const int wid  = threadIdx.x >> 6;
    const int col  = lane & 31;                        // n_local / m-row
    const int h    = lane >> 5;                        // k-half
    const int n0   = (blockIdx.x * 4 + wid) * 32;
    const int m0   = blockIdx.y * MCHUNK;

    // Q B-frag (loop-invariant): qb[n0+col], bytes [16h, 16h+16)
    const uint4 qraw = *(const uint4*)((const char*)qb + (size_t)(n0 + col) * 32 + h * 16);
    const sv8 qf = __builtin_bit_cast(sv8, qraw);

    const char* kbase = (const char*)kb + (size_t)(m0 + col) * 32 + h * 16;        // +1024/step
    const char* vbase = (const char*)vfrag + (size_t)(m0 >> 5) * 2048 + lane * 16; // +2048/step

    fv16 zerov, acc1, acc2;
#pragma unroll
    for (int i = 0; i < 16; ++i) { zerov[i] = 0.f; acc1[i] = 0.f; acc2[i] = 0.f; }

    uint4 kf = *(const uint4*)kbase;
    uint4 v1 = *(const uint4*)vbase;
    uint4 v2 = *(const uint4*)(vbase + 1024);

    for (int s = 0; s < MCHUNK / 32; ++s) {
        // unconditional prefetch (last-step over-read stays inside ws, unused)
        uint4 kf_n = *(const uint4*)(kbase + (size_t)(s + 1) * 1024);
        uint4 v1_n = *(const uint4*)(vbase + (size_t)(s + 1) * 2048);
        uint4 v2_n = *(const uint4*)(vbase + (size_t)(s + 1) * 2048 + 1024);

        fv16 S = MFMA32(__builtin_bit_cast(sv8, kf), qf, zerov);

        // relu + truncate-pack: p[i] = (bf16(S[2i]) , bf16(S[2i+1]))
        uint32 p[8];
#pragma unroll
        for (int i = 0; i < 8; ++i) {
            float e0 = fmaxf(S[2 * i], 0.f);
            float e1 = fmaxf(S[2 * i + 1], 0.f);
            p[i] = __builtin_amdgcn_perm(__builtin_bit_cast(uint32, e1),
                                         __builtin_bit_cast(uint32, e0), 0x07060302u);
        }
        // partner half's pairs (lane^32: same n, other h)
        uint32 sw[8];
#pragma unroll
        for (int i = 0; i < 8; ++i)
            sw[i] = __shfl_xor((unsigned int)p[i], 32, 64);

        uv4 b1 = { h ? sw[2] : p[0], h ? sw[3] : p[1],
                   h ? p[2] : sw[0], h ? p[3] : sw[1] };
        uv4 b2 = { h ? sw[6] : p[4], h ? sw[7] : p[5],
                   h ? p[6] : sw[4], h ? p[7] : sw[5] };

        acc1 = MFMA32(__builtin_bit_cast(sv8, v1), __builtin_bit_cast(sv8, b1), acc1);
        acc2 = MFMA32(__builtin_bit_cast(sv8, v2), __builtin_bit_cast(sv8, b2), acc2);

        kf = kf_n; v1 = v1_n; v2 = v2_n;
    }

    // Epilogue: f = (r&3)+8*(r>>2)+4h, n = n0+col; atomic into out[t][f][h][w]
    const int n  = n0 + col;
    const int t  = n >> 10;
    const int hw = n & 1023;
    float* op = out + (size_t)t * (NF * HW) + hw;
#pragma unroll
    for (int r = 0; r < 16; ++r) {
        int f = (r & 3) + 8 * (r >> 2) + 4 * h;
        if (f < NF)
            atomicAdd(op + f * HW, acc1[r] + acc2[r]);
    }
}

extern "C" void kernel_launch(void* const* d_in, const int* in_sizes, int n_in,
                              void* d_out, int out_size, void* d_ws, size_t ws_size,
                              hipStream_t stream)
{
    const float* in1 = (const float*)d_in[0];
    const float* in2 = (const float*)d_in[1];
    const float* w1  = (const float*)d_in[2];
    const float* b1  = (const float*)d_in[3];
    const float* w2  = (const float*)d_in[4];
    const float* b2  = (const float*)d_in[5];
    const float* w3  = (const float*)d_in[6];
    const float* b3  = (const float*)d_in[7];

    // ws layout: qb (256K) | kb (256K) | vfrag (512K)
    ushort16* qb    = (ushort16*)d_ws;
    ushort16* kb    = qb + (size_t)NTOT * FPAD;
    ushort16* vfrag = kb + (size_t)NTOT * FPAD;
    float*    out   = (float*)d_out;

    qkv_kernel<<<dim3(NTOT / 64, 2), 64, 0, stream>>>(
        in1, in2, w1, b1, w2, b2, w3, b3, qb, kb, vfrag, out);

    attn_mfma_kernel<<<dim3(64, MSPLIT), 256, 0, stream>>>(qb, kb, vfrag, out);
}